// Round 9
// baseline (427.590 us; speedup 1.0000x reference)
//
#include <hip/hip_runtime.h>
#include <hip/hip_bf16.h>
#include <cstdint>

#define MDIM 32768
#define NDIM 1024
#define KDIM 1024
#define KC   512   // compacted K (2:4 structured mask -> 2 of every 4 cols active)

typedef float          f32x4 __attribute__((ext_vector_type(4)));
typedef short          s16x8 __attribute__((ext_vector_type(8)));
typedef unsigned short u16x4 __attribute__((ext_vector_type(4)));
typedef unsigned short u16x8 __attribute__((ext_vector_type(8)));

typedef __attribute__((address_space(1))) unsigned int gu32;
typedef __attribute__((address_space(3))) unsigned int lu32;

// fp32 -> bf16 round-to-nearest-even (inputs are finite; no NaN handling needed)
__device__ __forceinline__ unsigned short f2bf(float f) {
  unsigned int u = __builtin_bit_cast(unsigned int, f);
  u += 0x7fffu + ((u >> 16) & 1u);
  return (unsigned short)(u >> 16);
}

// Branchless 2-of-4 column selection from mask values (exactly 2 of m0..m3 are
// nonzero). Covers all six patterns.
__device__ __forceinline__ float sel_first(f32x4 v, f32x4 m) {
  return m[0] != 0.0f ? v[0] : (m[1] != 0.0f ? v[1] : v[2]);
}
__device__ __forceinline__ float sel_second(f32x4 v, f32x4 m) {
  return m[3] != 0.0f ? v[3] : (m[2] != 0.0f ? v[2] : v[1]);
}

// async global->LDS, 16 bytes per lane (global_load_lds_dwordx4).
__device__ __forceinline__ void async16(const void* g, void* l) {
  __builtin_amdgcn_global_load_lds((gu32*)g, (lu32*)l, 16, 0, 0);
}

// Pass 1 (reverted to R0's measured-good form): fused compact+convert for X
// and W in ONE dispatch. Each thread: one 8-col window -> 4 compacted bf16.
// 32B coalesced read, 8B coalesced write; mask row-0 L1-hot. ~30 us, at the
// BW roofline for its 168 MB of traffic. Both in-GEMM fusion attempts (R5
// reg-staged: 143 us; R8 stage-phase: 260 us) were latency-bound losers:
// the X-load->select->cvt->LDS chain costs ~9 us/K-tile in ANY in-loop form.
__global__ __launch_bounds__(256) void compact_kernel(
    const float* __restrict__ x, const float* __restrict__ w,
    const float* __restrict__ msk,
    unsigned short* __restrict__ xb, unsigned short* __restrict__ wb) {
  const long long i = (long long)blockIdx.x * 256 + threadIdx.x;
  const long long nxw = (long long)MDIM * KDIM / 8;  // x windows
  const long long nww = (long long)NDIM * KDIM / 8;  // w windows
  if (i < nxw) {
    const int wi = (int)(i & 127);
    const long long row = i >> 7;
    const float* p = x + row * KDIM + wi * 8;
    f32x4 a = *(const f32x4*)p;
    f32x4 b = *(const f32x4*)(p + 4);
    f32x4 ma = *(const f32x4*)(msk + wi * 8);      // row-0 pattern
    f32x4 mb = *(const f32x4*)(msk + wi * 8 + 4);
    u16x4 o;
    o[0] = f2bf(sel_first(a, ma));
    o[1] = f2bf(sel_second(a, ma));
    o[2] = f2bf(sel_first(b, mb));
    o[3] = f2bf(sel_second(b, mb));
    ((u16x4*)xb)[i] = o;
  } else if (i < nxw + nww) {
    const long long j = i - nxw;
    const int wi = (int)(j & 127);
    const long long row = j >> 7;
    const float* p = w + row * KDIM + wi * 8;
    f32x4 a = *(const f32x4*)p;
    f32x4 b = *(const f32x4*)(p + 4);
    f32x4 moa = *(const f32x4*)(msk + row * KDIM + wi * 8);  // own-row mask
    f32x4 mob = *(const f32x4*)(msk + row * KDIM + wi * 8 + 4);
    f32x4 ma = *(const f32x4*)(msk + wi * 8);                // row-0 pattern
    f32x4 mb = *(const f32x4*)(msk + wi * 8 + 4);
#pragma unroll
    for (int t = 0; t < 4; ++t) { a[t] *= moa[t]; b[t] *= mob[t]; }  // faithful w*mask
    u16x4 o;
    o[0] = f2bf(sel_first(a, ma));
    o[1] = f2bf(sel_second(a, ma));
    o[2] = f2bf(sel_first(b, mb));
    o[3] = f2bf(sel_second(b, mb));
    ((u16x4*)wb)[j] = o;
  }
}

// ---------------------------------------------------------------------------
// Pass 2: C = Xb * Wb^T over compacted K. R0's proven 2-barrier m97 template
// with ONE parameter change: 256M x 128N tile, 8 waves (512 thr), BK=64.
// Rationale (K=512 has only 8 K-iters, so barrier/prologue amortization is
// the lever): staging bytes per MFMA drop 25% (48KB -> 2048 MFMA vs
// 32KB -> 1024), blocks halve to 1024 (fewer prologue rounds), LDS 48 KiB ->
// 3 blocks/CU x 8 waves = 24 waves/CU (vs 12) for cross-block hiding.
// acc stays [4][4] = 64 VGPR/wave. All swizzle / fragment / epilogue formulas
// are IDENTICAL to the verified R0 kernel; accumulation order unchanged.
// ---------------------------------------------------------------------------
__global__ __launch_bounds__(512, 6) void gemm_bigm_kernel(
    const unsigned short* __restrict__ Ab, const unsigned short* __restrict__ Bb,
    float* __restrict__ C) {
  __shared__ __align__(16) unsigned short lA[256 * 64];  // 32 KiB, swizzled
  __shared__ __align__(16) unsigned short lB[128 * 64];  // 16 KiB, swizzled

  const int tid = threadIdx.x;
  // XCD swizzle: 1024 blocks, %8==0 -> bijective. The 8 nt-sharers of one
  // A-panel are consecutive locals within an XCD -> panel (256 KB) + whole
  // Wb (1 MiB) stay in its 4 MB L2.
  const int g = blockIdx.x;
  const int xcd = g & 7;
  const int local = g >> 3;                // 0..127
  const int nt = local & 7;                // 8 N-tiles of 128
  const int mt = xcd * 16 + (local >> 3);  // 128 M-tiles of 256
  const int m0 = mt * 256, n0 = nt * 128;
  const int lane = tid & 63;
  const int wv = tid >> 6;                 // 0..7
  const int q = lane >> 4, r = lane & 15;
  const int wm = (wv >> 1) * 64;           // 4 M-slots of 64
  const int wn = (wv & 1) * 64;            // 2 N-slots of 64

  f32x4 acc[4][4] = {};

  // staging coords (same formulas as R0): linear chunk p -> (row, stored
  // chunk p&7); fetch global chunk cg = (p&7) ^ (row&7) so the swizzled
  // fragment reads are conflict-free.
  int parow[4], pacg[4];
#pragma unroll
  for (int i = 0; i < 4; ++i) {
    const int p = i * 512 + tid;           // 0..2047: 256 rows x 8 chunks
    parow[i] = p >> 3;
    pacg[i] = (p & 7) ^ (parow[i] & 7);
  }
  int pbrow[2], pbcg[2];
#pragma unroll
  for (int i = 0; i < 2; ++i) {
    const int p = i * 512 + tid;           // 0..1023: 128 rows x 8 chunks
    pbrow[i] = p >> 3;
    pbcg[i] = (p & 7) ^ (pbrow[i] & 7);
  }

  for (int kt = 0; kt < 8; ++kt) {         // KC/64 = 8 K-tiles
    const int k0 = kt * 64;
#pragma unroll
    for (int i = 0; i < 4; ++i) {
      const int p = i * 512 + tid;
      async16(Ab + (size_t)(m0 + parow[i]) * KC + k0 + pacg[i] * 8, &lA[p * 8]);
    }
#pragma unroll
    for (int i = 0; i < 2; ++i) {
      const int p = i * 512 + tid;
      async16(Bb + (size_t)(n0 + pbrow[i]) * KC + k0 + pbcg[i] * 8, &lB[p * 8]);
    }
    __syncthreads();  // drains vmcnt(0) for global_load_lds before LDS reads
#pragma unroll
    for (int kk = 0; kk < 2; ++kk) {
      s16x8 av[4], bv[4];
#pragma unroll
      for (int i = 0; i < 4; ++i) {
        const int ar = wm + 16 * i + r;
        av[i] = *(const s16x8*)&lA[ar * 64 + (((kk << 2) | q) ^ (ar & 7)) * 8];
        const int br = wn + 16 * i + r;
        bv[i] = *(const s16x8*)&lB[br * 64 + (((kk << 2) | q) ^ (br & 7)) * 8];
      }
#pragma unroll
      for (int i = 0; i < 4; ++i)
#pragma unroll
        for (int j = 0; j < 4; ++j)
          acc[i][j] = __builtin_amdgcn_mfma_f32_16x16x32_bf16(bv[j], av[i],
                                                              acc[i][j], 0, 0, 0);
    }
    __syncthreads();
  }

  // epilogue (transposed fragment, verified mapping, identical to R0):
  // acc[i][j][t] = C[m0+wm+16i+r][n0+wn+16j+4q+t] -> aligned f32x4 stores.
#pragma unroll
  for (int i = 0; i < 4; ++i) {
    const size_t rowoff = (size_t)(m0 + wm + 16 * i + r) * NDIM;
#pragma unroll
    for (int j = 0; j < 4; ++j) {
      const int col = n0 + wn + 16 * j + 4 * q;
      *(f32x4*)&C[rowoff + col] = acc[i][j];
    }
  }
}

// ---------------------------------------------------------------------------
// Fallback (ws too small): dense K=1024 GEMM, fp32 loads with in-reg convert
// + masked W. Unchanged from the verified 128^2 kernel.
// ---------------------------------------------------------------------------
__global__ __launch_bounds__(256) void gemm_dense_kernel(
    const float* __restrict__ Af, const float* __restrict__ Wf,
    const float* __restrict__ Mf, float* __restrict__ C) {
  __shared__ __align__(16) unsigned short lA[128 * 64];
  __shared__ __align__(16) unsigned short lB[128 * 64];

  constexpr int kstr = KDIM;
  constexpr int kiters = kstr / 64;

  const int tid = threadIdx.x;
  const int g = blockIdx.x;  // 2048 blocks
  const int xcd = g & 7;
  const int local = g >> 3;
  const int nt = local & 7;
  const int mt = xcd * 32 + (local >> 3);
  const int m0 = mt * 128, n0 = nt * 128;
  const int lane = tid & 63;
  const int wv = tid >> 6;
  const int q = lane >> 4, r = lane & 15;
  const int wm = (wv >> 1) * 64, wn = (wv & 1) * 64;

  f32x4 acc[4][4] = {};

  int prow[4], pcg[4];
#pragma unroll
  for (int i = 0; i < 4; ++i) {
    const int p = i * 256 + tid;
    prow[i] = p >> 3;
    pcg[i] = (p & 7) ^ (prow[i] & 7);
  }

  for (int kt = 0; kt < kiters; ++kt) {
    const int k0 = kt * 64;
#pragma unroll
    for (int i = 0; i < 4; ++i) {
      const int p = i * 256 + tid;
      const size_t offA = (size_t)(m0 + prow[i]) * kstr + k0 + pcg[i] * 8;
      const size_t offB = (size_t)(n0 + prow[i]) * kstr + k0 + pcg[i] * 8;
      f32x4 a0 = *(const f32x4*)(Af + offA);
      f32x4 a1 = *(const f32x4*)(Af + offA + 4);
      f32x4 w0 = *(const f32x4*)(Wf + offB);
      f32x4 w1 = *(const f32x4*)(Wf + offB + 4);
      f32x4 k0v = *(const f32x4*)(Mf + offB);
      f32x4 k1v = *(const f32x4*)(Mf + offB + 4);
      u16x8 oa, ob;
#pragma unroll
      for (int t = 0; t < 4; ++t) {
        oa[t] = f2bf(a0[t]); oa[4 + t] = f2bf(a1[t]);
        ob[t] = f2bf(w0[t] * k0v[t]); ob[4 + t] = f2bf(w1[t] * k1v[t]);
      }
      *(u16x8*)&lA[p * 8] = oa;
      *(u16x8*)&lB[p * 8] = ob;
    }
    __syncthreads();
#pragma unroll
    for (int kk = 0; kk < 2; ++kk) {
      s16x8 av[4], bv[4];
#pragma unroll
      for (int i = 0; i < 4; ++i) {
        const int ar = wm + 16 * i + r;
        av[i] = *(const s16x8*)&lA[ar * 64 + (((kk << 2) | q) ^ (ar & 7)) * 8];
        const int br = wn + 16 * i + r;
        bv[i] = *(const s16x8*)&lB[br * 64 + (((kk << 2) | q) ^ (br & 7)) * 8];
      }
#pragma unroll
      for (int i = 0; i < 4; ++i)
#pragma unroll
        for (int j = 0; j < 4; ++j)
          acc[i][j] = __builtin_amdgcn_mfma_f32_16x16x32_bf16(bv[j], av[i],
                                                              acc[i][j], 0, 0, 0);
    }
    __syncthreads();
  }

#pragma unroll
  for (int i = 0; i < 4; ++i) {
    const size_t rowoff = (size_t)(m0 + wm + 16 * i + r) * NDIM;
#pragma unroll
    for (int j = 0; j < 4; ++j) {
      const int col = n0 + wn + 16 * j + 4 * q;
      *(f32x4*)&C[rowoff + col] = acc[i][j];
    }
  }
}

extern "C" void kernel_launch(void* const* d_in, const int* in_sizes, int n_in,
                              void* d_out, int out_size, void* d_ws, size_t ws_size,
                              hipStream_t stream) {
  (void)in_sizes; (void)n_in; (void)out_size;
  const float* x  = (const float*)d_in[0];
  const float* w  = (const float*)d_in[1];
  const float* mk = (const float*)d_in[2];
  float* out = (float*)d_out;

  const size_t xb_bytes = (size_t)MDIM * KC * 2;  // 32 MiB
  const size_t wb_bytes = (size_t)NDIM * KC * 2;  // 1 MiB

  if (ws_size >= xb_bytes + wb_bytes) {
    unsigned short* xb = (unsigned short*)d_ws;
    unsigned short* wb = (unsigned short*)((char*)d_ws + xb_bytes);
    const long long totw = ((long long)MDIM * KDIM + (long long)NDIM * KDIM) / 8;
    const int cblocks = (int)((totw + 255) / 256);
    hipLaunchKernelGGL(compact_kernel, dim3(cblocks), dim3(256), 0, stream,
                       x, w, mk, xb, wb);
    const int gemm_blocks = (MDIM / 256) * (NDIM / 128);  // 1024
    hipLaunchKernelGGL(gemm_bigm_kernel, dim3(gemm_blocks), dim3(512), 0, stream,
                       xb, wb, out);
  } else {
    const int gemm_blocks = (MDIM / 128) * (NDIM / 128);  // 2048
    hipLaunchKernelGGL(gemm_dense_kernel, dim3(gemm_blocks), dim3(256), 0, stream,
                       x, w, mk, out);
  }
}

// Round 10
// 274.681 us; speedup vs baseline: 1.5567x; 1.5567x over previous
//
#include <hip/hip_runtime.h>
#include <hip/hip_bf16.h>
#include <cstdint>

#define MDIM 32768
#define NDIM 1024
#define KDIM 1024
#define KC   512   // compacted K (2:4 structured mask -> 2 of every 4 cols active)

typedef float          f32x4 __attribute__((ext_vector_type(4)));
typedef short          s16x8 __attribute__((ext_vector_type(8)));
typedef unsigned short u16x4 __attribute__((ext_vector_type(4)));
typedef unsigned short u16x8 __attribute__((ext_vector_type(8)));

typedef __attribute__((address_space(1))) unsigned int gu32;
typedef __attribute__((address_space(3))) unsigned int lu32;

// fp32 -> bf16 round-to-nearest-even (inputs are finite; no NaN handling needed)
__device__ __forceinline__ unsigned short f2bf(float f) {
  unsigned int u = __builtin_bit_cast(unsigned int, f);
  u += 0x7fffu + ((u >> 16) & 1u);
  return (unsigned short)(u >> 16);
}

// Branchless 2-of-4 column selection from mask values (exactly 2 of m0..m3 are
// nonzero). Covers all six patterns.
__device__ __forceinline__ float sel_first(f32x4 v, f32x4 m) {
  return m[0] != 0.0f ? v[0] : (m[1] != 0.0f ? v[1] : v[2]);
}
__device__ __forceinline__ float sel_second(f32x4 v, f32x4 m) {
  return m[3] != 0.0f ? v[3] : (m[2] != 0.0f ? v[2] : v[1]);
}

// async global->LDS, 16 bytes per lane (global_load_lds_dwordx4).
__device__ __forceinline__ void async16(const void* g, void* l) {
  __builtin_amdgcn_global_load_lds((gu32*)g, (lu32*)l, 16, 0, 0);
}

// Pass 1 (R0's measured-good form, unchanged): fused compact+convert for X
// and W in one dispatch. ~30 us, at the BW roofline for its 168 MB.
__global__ __launch_bounds__(256) void compact_kernel(
    const float* __restrict__ x, const float* __restrict__ w,
    const float* __restrict__ msk,
    unsigned short* __restrict__ xb, unsigned short* __restrict__ wb) {
  const long long i = (long long)blockIdx.x * 256 + threadIdx.x;
  const long long nxw = (long long)MDIM * KDIM / 8;  // x windows
  const long long nww = (long long)NDIM * KDIM / 8;  // w windows
  if (i < nxw) {
    const int wi = (int)(i & 127);
    const long long row = i >> 7;
    const float* p = x + row * KDIM + wi * 8;
    f32x4 a = *(const f32x4*)p;
    f32x4 b = *(const f32x4*)(p + 4);
    f32x4 ma = *(const f32x4*)(msk + wi * 8);      // row-0 pattern
    f32x4 mb = *(const f32x4*)(msk + wi * 8 + 4);
    u16x4 o;
    o[0] = f2bf(sel_first(a, ma));
    o[1] = f2bf(sel_second(a, ma));
    o[2] = f2bf(sel_first(b, mb));
    o[3] = f2bf(sel_second(b, mb));
    ((u16x4*)xb)[i] = o;
  } else if (i < nxw + nww) {
    const long long j = i - nxw;
    const int wi = (int)(j & 127);
    const long long row = j >> 7;
    const float* p = w + row * KDIM + wi * 8;
    f32x4 a = *(const f32x4*)p;
    f32x4 b = *(const f32x4*)(p + 4);
    f32x4 moa = *(const f32x4*)(msk + row * KDIM + wi * 8);  // own-row mask
    f32x4 mob = *(const f32x4*)(msk + row * KDIM + wi * 8 + 4);
    f32x4 ma = *(const f32x4*)(msk + wi * 8);                // row-0 pattern
    f32x4 mb = *(const f32x4*)(msk + wi * 8 + 4);
#pragma unroll
    for (int t = 0; t < 4; ++t) { a[t] *= moa[t]; b[t] *= mob[t]; }  // faithful w*mask
    u16x4 o;
    o[0] = f2bf(sel_first(a, ma));
    o[1] = f2bf(sel_second(a, ma));
    o[2] = f2bf(sel_first(b, mb));
    o[3] = f2bf(sel_second(b, mb));
    ((u16x4*)wb)[j] = o;
  }
}

// ---------------------------------------------------------------------------
// A/B round: the two GEMM templates split the M range. Disjoint C rows,
// sequential dispatches -> rocprof gives a clean per-dispatch comparison.
//
// A-side (rows 0..16383): R0's exact verified 128x128 / 4-wave / 2-barrier
// kernel, grid 1024. B-side (rows 16384..32767): the 256Mx128N / 8-wave
// variant from R9 -- whose 225 us was PURELY VGPR spills from
// __launch_bounds__(512,6) capping the allocator at 40 VGPRs (WRITE_SIZE
// 581 MB = 4.4x C). Fixed with (512,2): 256-VGPR budget, no spills.
// ---------------------------------------------------------------------------
__global__ __launch_bounds__(256) void gemm128_kernel(
    const unsigned short* __restrict__ Ab, const unsigned short* __restrict__ Bb,
    float* __restrict__ C) {
  __shared__ __align__(16) unsigned short lA[128 * 64];
  __shared__ __align__(16) unsigned short lB[128 * 64];

  const int tid = threadIdx.x;
  // 1024 blocks, %8==0 bijective XCD swizzle; covers M-tiles 0..127.
  const int g = blockIdx.x;
  const int xcd = g & 7;
  const int local = g >> 3;                // 0..127
  const int nt = local & 7;                // 8 N-tiles of 128
  const int mt = xcd * 16 + (local >> 3);  // 0..127
  const int m0 = mt * 128, n0 = nt * 128;
  const int lane = tid & 63;
  const int wv = tid >> 6;
  const int q = lane >> 4, r = lane & 15;
  const int wm = (wv >> 1) * 64, wn = (wv & 1) * 64;

  f32x4 acc[4][4] = {};

  int prow[4], pcg[4];
#pragma unroll
  for (int i = 0; i < 4; ++i) {
    const int p = i * 256 + tid;
    prow[i] = p >> 3;
    pcg[i] = (p & 7) ^ (prow[i] & 7);
  }

  for (int kt = 0; kt < 8; ++kt) {
    const int k0 = kt * 64;
#pragma unroll
    for (int i = 0; i < 4; ++i) {
      const int p = i * 256 + tid;
      async16(Ab + (size_t)(m0 + prow[i]) * KC + k0 + pcg[i] * 8, &lA[p * 8]);
      async16(Bb + (size_t)(n0 + prow[i]) * KC + k0 + pcg[i] * 8, &lB[p * 8]);
    }
    __syncthreads();
#pragma unroll
    for (int kk = 0; kk < 2; ++kk) {
      s16x8 av[4], bv[4];
#pragma unroll
      for (int i = 0; i < 4; ++i) {
        const int ar = wm + 16 * i + r;
        av[i] = *(const s16x8*)&lA[ar * 64 + (((kk << 2) | q) ^ (ar & 7)) * 8];
        const int br = wn + 16 * i + r;
        bv[i] = *(const s16x8*)&lB[br * 64 + (((kk << 2) | q) ^ (br & 7)) * 8];
      }
#pragma unroll
      for (int i = 0; i < 4; ++i)
#pragma unroll
        for (int j = 0; j < 4; ++j)
          acc[i][j] = __builtin_amdgcn_mfma_f32_16x16x32_bf16(bv[j], av[i],
                                                              acc[i][j], 0, 0, 0);
    }
    __syncthreads();
  }

#pragma unroll
  for (int i = 0; i < 4; ++i) {
    const size_t rowoff = (size_t)(m0 + wm + 16 * i + r) * NDIM;
#pragma unroll
    for (int j = 0; j < 4; ++j) {
      const int col = n0 + wn + 16 * j + 4 * q;
      *(f32x4*)&C[rowoff + col] = acc[i][j];
    }
  }
}

__global__ __launch_bounds__(512, 2) void gemm_bigm_kernel(
    const unsigned short* __restrict__ Ab, const unsigned short* __restrict__ Bb,
    float* __restrict__ C) {
  __shared__ __align__(16) unsigned short lA[256 * 64];  // 32 KiB, swizzled
  __shared__ __align__(16) unsigned short lB[128 * 64];  // 16 KiB, swizzled

  const int tid = threadIdx.x;
  // 512 blocks, %8==0 bijective; covers M rows 16384..32767 (64 tiles of 256).
  const int g = blockIdx.x;
  const int xcd = g & 7;
  const int local = g >> 3;                // 0..63
  const int nt = local & 7;                // 8 N-tiles of 128
  const int mt = xcd * 8 + (local >> 3);   // 0..63
  const int m0 = 16384 + mt * 256, n0 = nt * 128;
  const int lane = tid & 63;
  const int wv = tid >> 6;                 // 0..7
  const int q = lane >> 4, r = lane & 15;
  const int wm = (wv >> 1) * 64;           // 4 M-slots of 64
  const int wn = (wv & 1) * 64;            // 2 N-slots of 64

  f32x4 acc[4][4] = {};

  int parow[4], pacg[4];
#pragma unroll
  for (int i = 0; i < 4; ++i) {
    const int p = i * 512 + tid;           // 0..2047: 256 rows x 8 chunks
    parow[i] = p >> 3;
    pacg[i] = (p & 7) ^ (parow[i] & 7);
  }
  int pbrow[2], pbcg[2];
#pragma unroll
  for (int i = 0; i < 2; ++i) {
    const int p = i * 512 + tid;           // 0..1023: 128 rows x 8 chunks
    pbrow[i] = p >> 3;
    pbcg[i] = (p & 7) ^ (pbrow[i] & 7);
  }

  for (int kt = 0; kt < 8; ++kt) {         // KC/64 = 8 K-tiles
    const int k0 = kt * 64;
#pragma unroll
    for (int i = 0; i < 4; ++i) {
      const int p = i * 512 + tid;
      async16(Ab + (size_t)(m0 + parow[i]) * KC + k0 + pacg[i] * 8, &lA[p * 8]);
    }
#pragma unroll
    for (int i = 0; i < 2; ++i) {
      const int p = i * 512 + tid;
      async16(Bb + (size_t)(n0 + pbrow[i]) * KC + k0 + pbcg[i] * 8, &lB[p * 8]);
    }
    __syncthreads();
#pragma unroll
    for (int kk = 0; kk < 2; ++kk) {
      s16x8 av[4], bv[4];
#pragma unroll
      for (int i = 0; i < 4; ++i) {
        const int ar = wm + 16 * i + r;
        av[i] = *(const s16x8*)&lA[ar * 64 + (((kk << 2) | q) ^ (ar & 7)) * 8];
        const int br = wn + 16 * i + r;
        bv[i] = *(const s16x8*)&lB[br * 64 + (((kk << 2) | q) ^ (br & 7)) * 8];
      }
#pragma unroll
      for (int i = 0; i < 4; ++i)
#pragma unroll
        for (int j = 0; j < 4; ++j)
          acc[i][j] = __builtin_amdgcn_mfma_f32_16x16x32_bf16(bv[j], av[i],
                                                              acc[i][j], 0, 0, 0);
    }
    __syncthreads();
  }

#pragma unroll
  for (int i = 0; i < 4; ++i) {
    const size_t rowoff = (size_t)(m0 + wm + 16 * i + r) * NDIM;
#pragma unroll
    for (int j = 0; j < 4; ++j) {
      const int col = n0 + wn + 16 * j + 4 * q;
      *(f32x4*)&C[rowoff + col] = acc[i][j];
    }
  }
}

// ---------------------------------------------------------------------------
// Fallback (ws too small): dense K=1024 GEMM, unchanged.
// ---------------------------------------------------------------------------
__global__ __launch_bounds__(256) void gemm_dense_kernel(
    const float* __restrict__ Af, const float* __restrict__ Wf,
    const float* __restrict__ Mf, float* __restrict__ C) {
  __shared__ __align__(16) unsigned short lA[128 * 64];
  __shared__ __align__(16) unsigned short lB[128 * 64];

  constexpr int kstr = KDIM;
  constexpr int kiters = kstr / 64;

  const int tid = threadIdx.x;
  const int g = blockIdx.x;  // 2048 blocks
  const int xcd = g & 7;
  const int local = g >> 3;
  const int nt = local & 7;
  const int mt = xcd * 32 + (local >> 3);
  const int m0 = mt * 128, n0 = nt * 128;
  const int lane = tid & 63;
  const int wv = tid >> 6;
  const int q = lane >> 4, r = lane & 15;
  const int wm = (wv >> 1) * 64, wn = (wv & 1) * 64;

  f32x4 acc[4][4] = {};

  int prow[4], pcg[4];
#pragma unroll
  for (int i = 0; i < 4; ++i) {
    const int p = i * 256 + tid;
    prow[i] = p >> 3;
    pcg[i] = (p & 7) ^ (prow[i] & 7);
  }

  for (int kt = 0; kt < kiters; ++kt) {
    const int k0 = kt * 64;
#pragma unroll
    for (int i = 0; i < 4; ++i) {
      const int p = i * 256 + tid;
      const size_t offA = (size_t)(m0 + prow[i]) * kstr + k0 + pcg[i] * 8;
      const size_t offB = (size_t)(n0 + prow[i]) * kstr + k0 + pcg[i] * 8;
      f32x4 a0 = *(const f32x4*)(Af + offA);
      f32x4 a1 = *(const f32x4*)(Af + offA + 4);
      f32x4 w0 = *(const f32x4*)(Wf + offB);
      f32x4 w1 = *(const f32x4*)(Wf + offB + 4);
      f32x4 k0v = *(const f32x4*)(Mf + offB);
      f32x4 k1v = *(const f32x4*)(Mf + offB + 4);
      u16x8 oa, ob;
#pragma unroll
      for (int t = 0; t < 4; ++t) {
        oa[t] = f2bf(a0[t]); oa[4 + t] = f2bf(a1[t]);
        ob[t] = f2bf(w0[t] * k0v[t]); ob[4 + t] = f2bf(w1[t] * k1v[t]);
      }
      *(u16x8*)&lA[p * 8] = oa;
      *(u16x8*)&lB[p * 8] = ob;
    }
    __syncthreads();
#pragma unroll
    for (int kk = 0; kk < 2; ++kk) {
      s16x8 av[4], bv[4];
#pragma unroll
      for (int i = 0; i < 4; ++i) {
        const int ar = wm + 16 * i + r;
        av[i] = *(const s16x8*)&lA[ar * 64 + (((kk << 2) | q) ^ (ar & 7)) * 8];
        const int br = wn + 16 * i + r;
        bv[i] = *(const s16x8*)&lB[br * 64 + (((kk << 2) | q) ^ (br & 7)) * 8];
      }
#pragma unroll
      for (int i = 0; i < 4; ++i)
#pragma unroll
        for (int j = 0; j < 4; ++j)
          acc[i][j] = __builtin_amdgcn_mfma_f32_16x16x32_bf16(bv[j], av[i],
                                                              acc[i][j], 0, 0, 0);
    }
    __syncthreads();
  }

#pragma unroll
  for (int i = 0; i < 4; ++i) {
    const size_t rowoff = (size_t)(m0 + wm + 16 * i + r) * NDIM;
#pragma unroll
    for (int j = 0; j < 4; ++j) {
      const int col = n0 + wn + 16 * j + 4 * q;
      *(f32x4*)&C[rowoff + col] = acc[i][j];
    }
  }
}

extern "C" void kernel_launch(void* const* d_in, const int* in_sizes, int n_in,
                              void* d_out, int out_size, void* d_ws, size_t ws_size,
                              hipStream_t stream) {
  (void)in_sizes; (void)n_in; (void)out_size;
  const float* x  = (const float*)d_in[0];
  const float* w  = (const float*)d_in[1];
  const float* mk = (const float*)d_in[2];
  float* out = (float*)d_out;

  const size_t xb_bytes = (size_t)MDIM * KC * 2;  // 32 MiB
  const size_t wb_bytes = (size_t)NDIM * KC * 2;  // 1 MiB

  if (ws_size >= xb_bytes + wb_bytes) {
    unsigned short* xb = (unsigned short*)d_ws;
    unsigned short* wb = (unsigned short*)((char*)d_ws + xb_bytes);
    const long long totw = ((long long)MDIM * KDIM + (long long)NDIM * KDIM) / 8;
    const int cblocks = (int)((totw + 255) / 256);
    hipLaunchKernelGGL(compact_kernel, dim3(cblocks), dim3(256), 0, stream,
                       x, w, mk, xb, wb);
    // A/B split over M: rows 0..16383 via the verified 128^2 template,
    // rows 16384..32767 via the spill-fixed 256x128 template.
    hipLaunchKernelGGL(gemm128_kernel, dim3(1024), dim3(256), 0, stream,
                       xb, wb, out);
    hipLaunchKernelGGL(gemm_bigm_kernel, dim3(512), dim3(512), 0, stream,
                       xb, wb, out);
  } else {
    const int gemm_blocks = (MDIM / 128) * (NDIM / 128);  // 2048
    hipLaunchKernelGGL(gemm_dense_kernel, dim3(gemm_blocks), dim3(256), 0, stream,
                       x, w, mk, out);
  }
}

// Round 12
// 268.379 us; speedup vs baseline: 1.5932x; 1.0235x over previous
//
#include <hip/hip_runtime.h>
#include <hip/hip_bf16.h>
#include <cstdint>

#define MDIM 32768
#define NDIM 1024
#define KDIM 1024
#define KC   512   // compacted K (2:4 structured mask -> 2 of every 4 cols active)

typedef float          f32x4 __attribute__((ext_vector_type(4)));
typedef short          s16x8 __attribute__((ext_vector_type(8)));
typedef unsigned short u16x4 __attribute__((ext_vector_type(4)));
typedef unsigned short u16x8 __attribute__((ext_vector_type(8)));

typedef __attribute__((address_space(1))) unsigned int gu32;
typedef __attribute__((address_space(3))) unsigned int lu32;

// fp32 -> bf16 round-to-nearest-even (inputs are finite; no NaN handling needed)
__device__ __forceinline__ unsigned short f2bf(float f) {
  unsigned int u = __builtin_bit_cast(unsigned int, f);
  u += 0x7fffu + ((u >> 16) & 1u);
  return (unsigned short)(u >> 16);
}

// Branchless 2-of-4 column selection from mask values (exactly 2 of m0..m3 are
// nonzero). Covers all six patterns.
__device__ __forceinline__ float sel_first(f32x4 v, f32x4 m) {
  return m[0] != 0.0f ? v[0] : (m[1] != 0.0f ? v[1] : v[2]);
}
__device__ __forceinline__ float sel_second(f32x4 v, f32x4 m) {
  return m[3] != 0.0f ? v[3] : (m[2] != 0.0f ? v[2] : v[1]);
}

// async global->LDS, 16 bytes per lane (global_load_lds_dwordx4).
__device__ __forceinline__ void async16(const void* g, void* l) {
  __builtin_amdgcn_global_load_lds((gu32*)g, (lu32*)l, 16, 0, 0);
}

// Pass 1 (R0's measured-good form, unchanged): fused compact+convert for X
// and W in one dispatch. ~30 us, at the BW roofline for its ~170 MB.
__global__ __launch_bounds__(256) void compact_kernel(
    const float* __restrict__ x, const float* __restrict__ w,
    const float* __restrict__ msk,
    unsigned short* __restrict__ xb, unsigned short* __restrict__ wb) {
  const long long i = (long long)blockIdx.x * 256 + threadIdx.x;
  const long long nxw = (long long)MDIM * KDIM / 8;  // x windows
  const long long nww = (long long)NDIM * KDIM / 8;  // w windows
  if (i < nxw) {
    const int wi = (int)(i & 127);
    const long long row = i >> 7;
    const float* p = x + row * KDIM + wi * 8;
    f32x4 a = *(const f32x4*)p;
    f32x4 b = *(const f32x4*)(p + 4);
    f32x4 ma = *(const f32x4*)(msk + wi * 8);      // row-0 pattern
    f32x4 mb = *(const f32x4*)(msk + wi * 8 + 4);
    u16x4 o;
    o[0] = f2bf(sel_first(a, ma));
    o[1] = f2bf(sel_second(a, ma));
    o[2] = f2bf(sel_first(b, mb));
    o[3] = f2bf(sel_second(b, mb));
    ((u16x4*)xb)[i] = o;
  } else if (i < nxw + nww) {
    const long long j = i - nxw;
    const int wi = (int)(j & 127);
    const long long row = j >> 7;
    const float* p = w + row * KDIM + wi * 8;
    f32x4 a = *(const f32x4*)p;
    f32x4 b = *(const f32x4*)(p + 4);
    f32x4 moa = *(const f32x4*)(msk + row * KDIM + wi * 8);  // own-row mask
    f32x4 mob = *(const f32x4*)(msk + row * KDIM + wi * 8 + 4);
    f32x4 ma = *(const f32x4*)(msk + wi * 8);                // row-0 pattern
    f32x4 mb = *(const f32x4*)(msk + wi * 8 + 4);
#pragma unroll
    for (int t = 0; t < 4; ++t) { a[t] *= moa[t]; b[t] *= mob[t]; }  // faithful w*mask
    u16x4 o;
    o[0] = f2bf(sel_first(a, ma));
    o[1] = f2bf(sel_second(a, ma));
    o[2] = f2bf(sel_first(b, mb));
    o[3] = f2bf(sel_second(b, mb));
    ((u16x4*)wb)[j] = o;
  }
}

// ---------------------------------------------------------------------------
// Pass 2: C = Xb * Wb^T, 128x128 tile / 4 waves -- R0's verified template with
// ONE structural change: double-buffered LDS + counted vmcnt + raw s_barrier.
//
// Why (R10 model): the old stage -> __syncthreads() drained vmcnt(0) right
// after ISSUING the loads, exposing the full panel-fetch latency every K-tile
// (~5-8k cyc wall vs ~700 cyc compute; MfmaUtil ~22%). Tile-size A/B (R10)
// was exactly neutral -- per-iter latency x 8 iters dominates both shapes.
// Fix: stage tile kt+1 into buf^1 at loop top; s_waitcnt vmcnt(8) waits ONLY
// for tile kt's 8 loads (issued one iteration earlier -> latency covered by
// the previous compute phase); the fresh 8 stay in flight across barriers.
//
// Sync invariants:
//  - vmcnt(8) then s_barrier: every wave passed its own wait -> all tile-kt
//    data landed before any wave reads it.
//  - end-of-iter s_barrier: all waves done reading buf[cur] before the NEXT
//    iteration issues stage writes into that same buffer (WAR-safe: writes
//    are issued after the barrier, DMA cannot land before issue).
//  - numerics identical to R0 (same fragments, same MFMA order).
// ---------------------------------------------------------------------------
__global__ __launch_bounds__(256) void gemm_db_kernel(
    const unsigned short* __restrict__ Ab, const unsigned short* __restrict__ Bb,
    float* __restrict__ C) {
  __shared__ __align__(16) unsigned short lA[2][128 * 64];  // 2 x 16 KiB
  __shared__ __align__(16) unsigned short lB[2][128 * 64];  // 2 x 16 KiB

  const int tid = threadIdx.x;
  // XCD swizzle (R0's exact mapping): 2048 blocks, %8==0 -> bijective.
  const int g = blockIdx.x;
  const int xcd = g & 7;
  const int local = g >> 3;
  const int nt = local & 7;
  const int mt = xcd * 32 + (local >> 3);
  const int m0 = mt * 128, n0 = nt * 128;
  const int lane = tid & 63;
  const int wv = tid >> 6;
  const int q = lane >> 4, r = lane & 15;
  const int wm = (wv >> 1) * 64, wn = (wv & 1) * 64;

  f32x4 acc[4][4] = {};

  int prow[4], pcg[4];
#pragma unroll
  for (int i = 0; i < 4; ++i) {
    const int p = i * 256 + tid;
    prow[i] = p >> 3;
    pcg[i] = (p & 7) ^ (prow[i] & 7);
  }

  // stage one K-tile (8 global_load_lds instructions per wave)
  auto stage = [&](int kt, int buf) {
    const int k0 = kt * 64;
#pragma unroll
    for (int i = 0; i < 4; ++i) {
      const int p = i * 256 + tid;
      async16(Bb + (size_t)(n0 + prow[i]) * KC + k0 + pcg[i] * 8, &lB[buf][p * 8]);
      async16(Ab + (size_t)(m0 + prow[i]) * KC + k0 + pcg[i] * 8, &lA[buf][p * 8]);
    }
  };

  stage(0, 0);  // prologue

  for (int kt = 0; kt < 8; ++kt) {
    const int cur = kt & 1;
    if (kt < 7) {
      stage(kt + 1, cur ^ 1);  // prefetch next tile; stays in flight
      // wait only for tile kt's 8 loads (the 8 oldest); 8 newest remain.
      asm volatile("s_waitcnt vmcnt(8)" ::: "memory");
    } else {
      asm volatile("s_waitcnt vmcnt(0)" ::: "memory");
    }
    __builtin_amdgcn_s_barrier();       // all waves: tile kt fully landed
    __builtin_amdgcn_sched_barrier(0);  // no hoisting of ds_reads above

    const unsigned short* sA = &lA[cur][0];
    const unsigned short* sB = &lB[cur][0];
#pragma unroll
    for (int kk = 0; kk < 2; ++kk) {
      s16x8 av[4], bv[4];
#pragma unroll
      for (int i = 0; i < 4; ++i) {
        const int ar = wm + 16 * i + r;
        av[i] = *(const s16x8*)&sA[ar * 64 + (((kk << 2) | q) ^ (ar & 7)) * 8];
        const int br = wn + 16 * i + r;
        bv[i] = *(const s16x8*)&sB[br * 64 + (((kk << 2) | q) ^ (br & 7)) * 8];
      }
#pragma unroll
      for (int i = 0; i < 4; ++i)
#pragma unroll
        for (int j = 0; j < 4; ++j)
          acc[i][j] = __builtin_amdgcn_mfma_f32_16x16x32_bf16(bv[j], av[i],
                                                              acc[i][j], 0, 0, 0);
    }
    __builtin_amdgcn_sched_barrier(0);  // no sinking of ds_reads below
    __builtin_amdgcn_s_barrier();       // readers done before buf[cur] is
  }                                     // overwritten by next iter's stage

  // epilogue (transposed fragment, verified mapping, identical to R0)
#pragma unroll
  for (int i = 0; i < 4; ++i) {
    const size_t rowoff = (size_t)(m0 + wm + 16 * i + r) * NDIM;
#pragma unroll
    for (int j = 0; j < 4; ++j) {
      const int col = n0 + wn + 16 * j + 4 * q;
      *(f32x4*)&C[rowoff + col] = acc[i][j];
    }
  }
}

// ---------------------------------------------------------------------------
// Fallback (ws too small): dense K=1024 GEMM, unchanged.
// ---------------------------------------------------------------------------
__global__ __launch_bounds__(256) void gemm_dense_kernel(
    const float* __restrict__ Af, const float* __restrict__ Wf,
    const float* __restrict__ Mf, float* __restrict__ C) {
  __shared__ __align__(16) unsigned short lA[128 * 64];
  __shared__ __align__(16) unsigned short lB[128 * 64];

  constexpr int kstr = KDIM;
  constexpr int kiters = kstr / 64;

  const int tid = threadIdx.x;
  const int g = blockIdx.x;  // 2048 blocks
  const int xcd = g & 7;
  const int local = g >> 3;
  const int nt = local & 7;
  const int mt = xcd * 32 + (local >> 3);
  const int m0 = mt * 128, n0 = nt * 128;
  const int lane = tid & 63;
  const int wv = tid >> 6;
  const int q = lane >> 4, r = lane & 15;
  const int wm = (wv >> 1) * 64, wn = (wv & 1) * 64;

  f32x4 acc[4][4] = {};

  int prow[4], pcg[4];
#pragma unroll
  for (int i = 0; i < 4; ++i) {
    const int p = i * 256 + tid;
    prow[i] = p >> 3;
    pcg[i] = (p & 7) ^ (prow[i] & 7);
  }

  for (int kt = 0; kt < kiters; ++kt) {
    const int k0 = kt * 64;
#pragma unroll
    for (int i = 0; i < 4; ++i) {
      const int p = i * 256 + tid;
      const size_t offA = (size_t)(m0 + prow[i]) * kstr + k0 + pcg[i] * 8;
      const size_t offB = (size_t)(n0 + prow[i]) * kstr + k0 + pcg[i] * 8;
      f32x4 a0 = *(const f32x4*)(Af + offA);
      f32x4 a1 = *(const f32x4*)(Af + offA + 4);
      f32x4 w0 = *(const f32x4*)(Wf + offB);
      f32x4 w1 = *(const f32x4*)(Wf + offB + 4);
      f32x4 k0v = *(const f32x4*)(Mf + offB);
      f32x4 k1v = *(const f32x4*)(Mf + offB + 4);
      u16x8 oa, ob;
#pragma unroll
      for (int t = 0; t < 4; ++t) {
        oa[t] = f2bf(a0[t]); oa[4 + t] = f2bf(a1[t]);
        ob[t] = f2bf(w0[t] * k0v[t]); ob[4 + t] = f2bf(w1[t] * k1v[t]);
      }
      *(u16x8*)&lA[p * 8] = oa;
      *(u16x8*)&lB[p * 8] = ob;
    }
    __syncthreads();
#pragma unroll
    for (int kk = 0; kk < 2; ++kk) {
      s16x8 av[4], bv[4];
#pragma unroll
      for (int i = 0; i < 4; ++i) {
        const int ar = wm + 16 * i + r;
        av[i] = *(const s16x8*)&lA[ar * 64 + (((kk << 2) | q) ^ (ar & 7)) * 8];
        const int br = wn + 16 * i + r;
        bv[i] = *(const s16x8*)&lB[br * 64 + (((kk << 2) | q) ^ (br & 7)) * 8];
      }
#pragma unroll
      for (int i = 0; i < 4; ++i)
#pragma unroll
        for (int j = 0; j < 4; ++j)
          acc[i][j] = __builtin_amdgcn_mfma_f32_16x16x32_bf16(bv[j], av[i],
                                                              acc[i][j], 0, 0, 0);
    }
    __syncthreads();
  }

#pragma unroll
  for (int i = 0; i < 4; ++i) {
    const size_t rowoff = (size_t)(m0 + wm + 16 * i + r) * NDIM;
#pragma unroll
    for (int j = 0; j < 4; ++j) {
      const int col = n0 + wn + 16 * j + 4 * q;
      *(f32x4*)&C[rowoff + col] = acc[i][j];
    }
  }
}

extern "C" void kernel_launch(void* const* d_in, const int* in_sizes, int n_in,
                              void* d_out, int out_size, void* d_ws, size_t ws_size,
                              hipStream_t stream) {
  (void)in_sizes; (void)n_in; (void)out_size;
  const float* x  = (const float*)d_in[0];
  const float* w  = (const float*)d_in[1];
  const float* mk = (const float*)d_in[2];
  float* out = (float*)d_out;

  const size_t xb_bytes = (size_t)MDIM * KC * 2;  // 32 MiB
  const size_t wb_bytes = (size_t)NDIM * KC * 2;  // 1 MiB

  if (ws_size >= xb_bytes + wb_bytes) {
    unsigned short* xb = (unsigned short*)d_ws;
    unsigned short* wb = (unsigned short*)((char*)d_ws + xb_bytes);
    const long long totw = ((long long)MDIM * KDIM + (long long)NDIM * KDIM) / 8;
    const int cblocks = (int)((totw + 255) / 256);
    hipLaunchKernelGGL(compact_kernel, dim3(cblocks), dim3(256), 0, stream,
                       x, w, mk, xb, wb);
    const int gemm_blocks = (MDIM / 128) * (NDIM / 128);  // 2048
    hipLaunchKernelGGL(gemm_db_kernel, dim3(gemm_blocks), dim3(256), 0, stream,
                       xb, wb, out);
  } else {
    const int gemm_blocks = (MDIM / 128) * (NDIM / 128);  // 2048
    hipLaunchKernelGGL(gemm_dense_kernel, dim3(gemm_blocks), dim3(256), 0, stream,
                       x, w, mk, out);
  }
}